// Round 3
// baseline (349.561 us; speedup 1.0000x reference)
//
#include <hip/hip_runtime.h>

#define HID 10
#define STEPS 512

typedef __attribute__((ext_vector_type(2))) float v2f;

// broadcast lane ((lane&0x10)|F) within each 32-lane half -> all lanes of each 16-group
// (used only in the one-time t=0 peel now)
template<int F>
static __device__ __forceinline__ float swz(float v) {
    return __int_as_float(__builtin_amdgcn_ds_swizzle(__float_as_int(v), (F << 5) | 0x10));
}

// DPP row_ror:J — rotate within each 16-lane row on the VALU pipe (no LDS).
// Direction convention is irrelevant: weight tables are built from a
// self-calibrated source-index probe using the SAME ctrl (irot on lane id).
template<int J>
static __device__ __forceinline__ float frot(float v) {
    return __int_as_float(__builtin_amdgcn_update_dpp(
        0, __float_as_int(v), 0x120 + J, 0xF, 0xF, true));
}
template<int J>
static __device__ __forceinline__ int irot(int v) {
    return __builtin_amdgcn_update_dpp(0, v, 0x120 + J, 0xF, 0xF, true);
}

// Lane-parallel fused GRU decoder, 1 feature per lane, 4 batches per wave.
//   batch = blockIdx*4 + (lane>>4); f = lane&15 (f>=10: zero-padded, stores masked)
// Per-step h broadcast: 15 independent DPP row-rotations (VALU) instead of
// 10 ds_swizzle (LDS pipe shared by 4 SIMDs/CU). Dots are 16-term (6 zero-weighted).
// PIPELINED STORE: o_t = l1(h_{t+1}); iteration t stores o_{t-1}, epilogue stores o_511.
// amdgpu_waves_per_eu(2,2): grid is structurally 2 waves/SIMD; pinning min=max=2
// gives the allocator the full 256-VGPR budget so the 80-reg weight tables stay
// RESIDENT. (Round 2 at VGPR=76 was provably re-parking/rematerializing them
// every iteration — the +28% VALU busy-time regression.)
__attribute__((amdgpu_waves_per_eu(2, 2)))
__global__ __launch_bounds__(64) void gru_decoder_kernel(
    const float* __restrict__ hidden, const float* __restrict__ w_ih,
    const float* __restrict__ w_hh, const float* __restrict__ b_ih,
    const float* __restrict__ b_hh, const float* __restrict__ l1_w,
    const float* __restrict__ l1_b, const float* __restrict__ l2_w,
    const float* __restrict__ l2_b, float* __restrict__ out)
{
    __shared__ float sWx[640];   // l2_w @ l1_w (64x10)
    __shared__ float sbx[64];    // l2_w @ l1_b + l2_b
    __shared__ float sWgi[300];  // w_ih @ Wx (30x10)
    __shared__ float sbgi[30];   // b_ih + w_ih @ bx
    __shared__ float sWhh[300];  // w_hh copy (t=0 peel + weight build)

    const int lane = threadIdx.x;
    const int f    = lane & 15;
    const int b    = blockIdx.x * 4 + (lane >> 4);
    const bool ok  = (f < HID);
    const int fi   = ok ? f : 0;          // clamped index for safe reads

    // ---- preamble: fused weights (fp32, cooperative) ----
    for (int e = lane; e < 640; e += 64) {
        int i = e / 10, j = e - i * 10;
        float acc = 0.f;
        #pragma unroll
        for (int k = 0; k < 10; ++k) acc += l2_w[i * 10 + k] * l1_w[k * 10 + j];
        sWx[e] = acc;
    }
    {
        float acc = l2_b[lane];
        #pragma unroll
        for (int k = 0; k < 10; ++k) acc += l2_w[lane * 10 + k] * l1_b[k];
        sbx[lane] = acc;
    }
    for (int e = lane; e < 300; e += 64) sWhh[e] = w_hh[e];
    __syncthreads();
    for (int e = lane; e < 300; e += 64) {
        int m = e / 10, j = e - m * 10;
        float acc = 0.f;
        for (int k = 0; k < 64; ++k) acc += w_ih[m * 64 + k] * sWx[k * 10 + j];
        sWgi[e] = acc;
    }
    if (lane < 30) {
        float acc = b_ih[lane];
        for (int k = 0; k < 64; ++k) acc += w_ih[lane * 64 + k] * sbx[k];
        sbgi[lane] = acc;
    }
    __syncthreads();

    const float LOG2E = 1.4426950408889634f;
    const float S2    = 2.f * LOG2E;

    // ---- self-calibrated rotation source indices (within each 16-row) ----
    int sidx[16];
    sidx[0]  = f;
    sidx[1]  = irot<1>(f);   sidx[2]  = irot<2>(f);   sidx[3]  = irot<3>(f);
    sidx[4]  = irot<4>(f);   sidx[5]  = irot<5>(f);   sidx[6]  = irot<6>(f);
    sidx[7]  = irot<7>(f);   sidx[8]  = irot<8>(f);   sidx[9]  = irot<9>(f);
    sidx[10] = irot<10>(f);  sidx[11] = irot<11>(f);  sidx[12] = irot<12>(f);
    sidx[13] = irot<13>(f);  sidx[14] = irot<14>(f);  sidx[15] = irot<15>(f);

    // ---- per-lane rotated weight tables (16 terms; zeros for padded sources) ----
    v2f wrz[16], wnn[16];
    float wo[16];
    #pragma unroll
    for (int j = 0; j < 16; ++j) {
        int s   = sidx[j];
        bool va = ok && (s < HID);
        int sc  = (s < HID) ? s : 0;
        float grz_r = -(sWgi[fi * 10 + sc] + sWhh[fi * 10 + sc]) * LOG2E;
        float grz_z = -(sWgi[(10 + fi) * 10 + sc] + sWhh[(10 + fi) * 10 + sc]) * LOG2E;
        float gni   = sWgi[(20 + fi) * 10 + sc] * S2;
        float gnh   = sWhh[(20 + fi) * 10 + sc] * S2;
        wrz[j] = va ? v2f{grz_r, grz_z} : v2f{0.f, 0.f};
        wnn[j] = va ? v2f{gni, gnh}     : v2f{0.f, 0.f};
        wo[j]  = va ? l1_w[fi * 10 + sc] : 0.f;
    }

    const v2f brz = ok ? v2f{-(sbgi[fi] + b_hh[fi]) * LOG2E,
                             -(sbgi[10 + fi] + b_hh[10 + fi]) * LOG2E}
                       : v2f{0.f, 0.f};
    const v2f bnn = ok ? v2f{sbgi[20 + fi] * S2, b_hh[20 + fi] * S2} : v2f{0.f, 0.f};
    const float bo = ok ? l1_b[fi] : 0.f;
    // t=0 peel biases (gi = b_ih only)
    const v2f brz0 = ok ? v2f{-(b_ih[fi] + b_hh[fi]) * LOG2E,
                              -(b_ih[10 + fi] + b_hh[10 + fi]) * LOG2E}
                        : v2f{0.f, 0.f};
    const float bni0 = ok ? b_ih[20 + fi] * S2 : 0.f;

    // ---- initial h (one feature per lane; f>=10 stays exactly 0) ----
    float h = ok ? hidden[(size_t)b * HID + f] : 0.f;

    float* pb = out + (size_t)b * (STEPS * HID) + (size_t)(STEPS - 1) * HID + f;

    // ---- t = 0 peeled: gi = b_ih only (x_0 = 0); raw w_hh dots from LDS ----
    // Produces h1. Its output o_0 = l1(h1) is stored by the first loop iteration.
    {
        float ha[10];
        ha[0] = swz<0>(h); ha[1] = swz<1>(h); ha[2] = swz<2>(h);
        ha[3] = swz<3>(h); ha[4] = swz<4>(h); ha[5] = swz<5>(h);
        ha[6] = swz<6>(h); ha[7] = swz<7>(h); ha[8] = swz<8>(h);
        ha[9] = swz<9>(h);
        float pr = 0.f, pz = 0.f, ph = 0.f;
        #pragma unroll
        for (int k = 0; k < 10; ++k) {
            pr += sWhh[fi * 10 + k] * ha[k];
            pz += sWhh[(10 + fi) * 10 + k] * ha[k];
            ph += sWhh[(20 + fi) * 10 + k] * ha[k];
        }
        float vr = brz0.x - pr * LOG2E;
        float vz = brz0.y - pz * LOG2E;
        float r = __builtin_amdgcn_rcpf(1.f + __builtin_amdgcn_exp2f(vr));
        float z = __builtin_amdgcn_rcpf(1.f + __builtin_amdgcn_exp2f(vz));
        float y = bni0 + r * (ph * S2 + bnn.y);
        float n = 1.f - 2.f * __builtin_amdgcn_rcpf(1.f + __builtin_amdgcn_exp2f(y));
        h = ok ? (n + z * (h - n)) : 0.f;
    }

    // ---- t = 1 .. 511 : rotation broadcast; iteration t stores o_{t-1} ----
    #pragma unroll 1
    for (int t = 1; t < STEPS; ++t) {
        float rh[16];
        rh[0]  = h;
        rh[1]  = frot<1>(h);   rh[2]  = frot<2>(h);   rh[3]  = frot<3>(h);
        rh[4]  = frot<4>(h);   rh[5]  = frot<5>(h);   rh[6]  = frot<6>(h);
        rh[7]  = frot<7>(h);   rh[8]  = frot<8>(h);   rh[9]  = frot<9>(h);
        rh[10] = frot<10>(h);  rh[11] = frot<11>(h);  rh[12] = frot<12>(h);
        rh[13] = frot<13>(h);  rh[14] = frot<14>(h);  rh[15] = frot<15>(h);

        v2f a0 = brz, n0 = bnn;
        v2f a1 = {0.f, 0.f}, n1 = {0.f, 0.f};
        float o0 = bo, o1 = 0.f;
        #pragma unroll
        for (int j = 0; j < 8; ++j) {
            v2f hj = {rh[j], rh[j]};
            a0 += wrz[j] * hj;
            n0 += wnn[j] * hj;
            o0 = __builtin_fmaf(wo[j], rh[j], o0);
        }
        #pragma unroll
        for (int j = 8; j < 16; ++j) {
            v2f hj = {rh[j], rh[j]};
            a1 += wrz[j] * hj;
            n1 += wnn[j] * hj;
            o1 = __builtin_fmaf(wo[j], rh[j], o1);
        }
        v2f arz = a0 + a1;
        v2f ann = n0 + n1;
        float o = o0 + o1;          // = l1(h_t) = o_{t-1}

        float r = __builtin_amdgcn_rcpf(1.f + __builtin_amdgcn_exp2f(arz.x));
        float z = __builtin_amdgcn_rcpf(1.f + __builtin_amdgcn_exp2f(arz.y));
        float zh  = z * h;        // off the n-path: issue early
        float omz = 1.f - z;
        float y = __builtin_fmaf(r, ann.y, ann.x);
        float n = 1.f - 2.f * __builtin_amdgcn_rcpf(1.f + __builtin_amdgcn_exp2f(y));
        h = __builtin_fmaf(n, omz, zh);   // == n + z*(h-n); padded lanes stay 0

        if (ok) pb[0] = o;                 // store o_{t-1} (position STEPS-t)
        pb -= HID;
    }

    // ---- epilogue: o_511 = l1(h_512) at position 0 ----
    {
        float rh[16];
        rh[0]  = h;
        rh[1]  = frot<1>(h);   rh[2]  = frot<2>(h);   rh[3]  = frot<3>(h);
        rh[4]  = frot<4>(h);   rh[5]  = frot<5>(h);   rh[6]  = frot<6>(h);
        rh[7]  = frot<7>(h);   rh[8]  = frot<8>(h);   rh[9]  = frot<9>(h);
        rh[10] = frot<10>(h);  rh[11] = frot<11>(h);  rh[12] = frot<12>(h);
        rh[13] = frot<13>(h);  rh[14] = frot<14>(h);  rh[15] = frot<15>(h);
        float o0 = bo, o1 = 0.f;
        #pragma unroll
        for (int j = 0; j < 8; ++j)  o0 = __builtin_fmaf(wo[j], rh[j], o0);
        #pragma unroll
        for (int j = 8; j < 16; ++j) o1 = __builtin_fmaf(wo[j], rh[j], o1);
        if (ok) pb[0] = o0 + o1;
    }
}

extern "C" void kernel_launch(void* const* d_in, const int* in_sizes, int n_in,
                              void* d_out, int out_size, void* d_ws, size_t ws_size,
                              hipStream_t stream) {
    (void)in_sizes; (void)n_in; (void)d_ws; (void)ws_size; (void)out_size;
    dim3 grid(2048), block(64);   // 4 batches/wave, 2048 waves -> 2 waves per SIMD
    gru_decoder_kernel<<<grid, block, 0, stream>>>(
        (const float*)d_in[0], (const float*)d_in[1], (const float*)d_in[2],
        (const float*)d_in[3], (const float*)d_in[4], (const float*)d_in[5],
        (const float*)d_in[6], (const float*)d_in[7], (const float*)d_in[8],
        (float*)d_out);
}

// Round 4
// 295.260 us; speedup vs baseline: 1.1839x; 1.1839x over previous
//
#include <hip/hip_runtime.h>

#define HID 10
#define STEPS 512

typedef __attribute__((ext_vector_type(2))) float v2f;

// broadcast lane ((lane&0x10)|F) within each 32-lane half -> all lanes of each 16-group
template<int F>
static __device__ __forceinline__ float swz(float v) {
    return __int_as_float(__builtin_amdgcn_ds_swizzle(__float_as_int(v), (F << 5) | 0x10));
}

// Lane-parallel fused GRU decoder, 1 feature per lane, 4 batches per wave.
//   batch = blockIdx*4 + (lane>>4); f = lane&15 (f>=10: zero-padded, stores masked)
// v4: Round-0 skeleton (ds_swizzle, 10-term dots) + two latency fixes:
//  (a) dots packed ACROSS K (even/odd pairs): each 10-term dot = 5-deep
//      v_pk_fma_f32 chain + 1 fold, 5 independent chains (r,z,ni,nh,o) —
//      halves the dot-dependency depth at equal instruction count.
//  (b) pipelined store: o_t = l1(h_{t+1}); iteration t computes o_{t-1} from
//      the SAME gathered h as the gates (parallel, off the critical path);
//      epilogue stores o_511. (Rounds 2/3 proved this scheme correct.)
// DPP experiment (R2/R3) reverted: 16-term padding cost more issue than the
// DS latency it removed (183 -> 228 us).
__global__ __launch_bounds__(64, 2) void gru_decoder_kernel(
    const float* __restrict__ hidden, const float* __restrict__ w_ih,
    const float* __restrict__ w_hh, const float* __restrict__ b_ih,
    const float* __restrict__ b_hh, const float* __restrict__ l1_w,
    const float* __restrict__ l1_b, const float* __restrict__ l2_w,
    const float* __restrict__ l2_b, float* __restrict__ out)
{
    __shared__ float sWx[640];   // l2_w @ l1_w (64x10)
    __shared__ float sbx[64];    // l2_w @ l1_b + l2_b
    __shared__ float sWgi[300];  // w_ih @ Wx (30x10)
    __shared__ float sbgi[30];   // b_ih + w_ih @ bx
    __shared__ float sWhh[300];  // w_hh copy (t=0 peel + weight build)

    const int lane = threadIdx.x;
    const int f    = lane & 15;
    const int b    = blockIdx.x * 4 + (lane >> 4);
    const bool ok  = (f < HID);
    const int fi   = ok ? f : 0;          // clamped index for safe reads

    // ---- preamble: fused weights (fp32, cooperative) ----
    for (int e = lane; e < 640; e += 64) {
        int i = e / 10, j = e - i * 10;
        float acc = 0.f;
        #pragma unroll
        for (int k = 0; k < 10; ++k) acc += l2_w[i * 10 + k] * l1_w[k * 10 + j];
        sWx[e] = acc;
    }
    {
        float acc = l2_b[lane];
        #pragma unroll
        for (int k = 0; k < 10; ++k) acc += l2_w[lane * 10 + k] * l1_b[k];
        sbx[lane] = acc;
    }
    for (int e = lane; e < 300; e += 64) sWhh[e] = w_hh[e];
    __syncthreads();
    for (int e = lane; e < 300; e += 64) {
        int m = e / 10, j = e - m * 10;
        float acc = 0.f;
        for (int k = 0; k < 64; ++k) acc += w_ih[m * 64 + k] * sWx[k * 10 + j];
        sWgi[e] = acc;
    }
    if (lane < 30) {
        float acc = b_ih[lane];
        for (int k = 0; k < 64; ++k) acc += w_ih[lane * 64 + k] * sbx[k];
        sbgi[lane] = acc;
    }
    __syncthreads();

    const float LOG2E = 1.4426950408889634f;
    const float S2    = 2.f * LOG2E;

    // ---- per-lane weights (feature fi), packed across k (even/odd) ----
    // r,z rows pre-scaled by -LOG2E (sigmoid via exp2 of negated arg);
    // ni,nh rows pre-scaled by 2*LOG2E (tanh via exp2).
    v2f wr2[5], wz2[5], wi2[5], wh2[5], wo2[5];
    #pragma unroll
    for (int k2 = 0; k2 < 5; ++k2) {
        int k0 = 2 * k2, k1 = 2 * k2 + 1;
        float r0 = -(sWgi[fi * 10 + k0] + sWhh[fi * 10 + k0]) * LOG2E;
        float r1 = -(sWgi[fi * 10 + k1] + sWhh[fi * 10 + k1]) * LOG2E;
        float z0 = -(sWgi[(10 + fi) * 10 + k0] + sWhh[(10 + fi) * 10 + k0]) * LOG2E;
        float z1 = -(sWgi[(10 + fi) * 10 + k1] + sWhh[(10 + fi) * 10 + k1]) * LOG2E;
        float i0 = sWgi[(20 + fi) * 10 + k0] * S2;
        float i1 = sWgi[(20 + fi) * 10 + k1] * S2;
        float hh0 = sWhh[(20 + fi) * 10 + k0] * S2;
        float hh1 = sWhh[(20 + fi) * 10 + k1] * S2;
        float o0 = l1_w[fi * 10 + k0];
        float o1 = l1_w[fi * 10 + k1];
        wr2[k2] = ok ? v2f{r0, r1}   : v2f{0.f, 0.f};
        wz2[k2] = ok ? v2f{z0, z1}   : v2f{0.f, 0.f};
        wi2[k2] = ok ? v2f{i0, i1}   : v2f{0.f, 0.f};
        wh2[k2] = ok ? v2f{hh0, hh1} : v2f{0.f, 0.f};
        wo2[k2] = ok ? v2f{o0, o1}   : v2f{0.f, 0.f};
    }
    const float br = ok ? -(sbgi[fi] + b_hh[fi]) * LOG2E : 0.f;
    const float bz = ok ? -(sbgi[10 + fi] + b_hh[10 + fi]) * LOG2E : 0.f;
    const float bi = ok ? sbgi[20 + fi] * S2 : 0.f;
    const float bh = ok ? b_hh[20 + fi] * S2 : 0.f;
    const float bo = ok ? l1_b[fi] : 0.f;
    // t=0 peel biases (gi = b_ih only)
    const float br0_ = ok ? -(b_ih[fi] + b_hh[fi]) * LOG2E : 0.f;
    const float bz0_ = ok ? -(b_ih[10 + fi] + b_hh[10 + fi]) * LOG2E : 0.f;
    const float bni0 = ok ? b_ih[20 + fi] * S2 : 0.f;

    // ---- initial h (one feature per lane; f>=10 stays exactly 0) ----
    float h = ok ? hidden[(size_t)b * HID + f] : 0.f;

    float* pb = out + (size_t)b * (STEPS * HID) + (size_t)(STEPS - 1) * HID + f;

    // ---- t = 0 peeled: gi = b_ih only (x_0 = 0); raw w_hh dots from LDS ----
    // Produces h1. o_0 = l1(h1) is stored by the first loop iteration.
    {
        float ha[10];
        ha[0] = swz<0>(h); ha[1] = swz<1>(h); ha[2] = swz<2>(h);
        ha[3] = swz<3>(h); ha[4] = swz<4>(h); ha[5] = swz<5>(h);
        ha[6] = swz<6>(h); ha[7] = swz<7>(h); ha[8] = swz<8>(h);
        ha[9] = swz<9>(h);
        float pr = 0.f, pz = 0.f, ph = 0.f;
        #pragma unroll
        for (int k = 0; k < 10; ++k) {
            pr += sWhh[fi * 10 + k] * ha[k];
            pz += sWhh[(10 + fi) * 10 + k] * ha[k];
            ph += sWhh[(20 + fi) * 10 + k] * ha[k];
        }
        float vr = br0_ - pr * LOG2E;
        float vz = bz0_ - pz * LOG2E;
        float r = __builtin_amdgcn_rcpf(1.f + __builtin_amdgcn_exp2f(vr));
        float z = __builtin_amdgcn_rcpf(1.f + __builtin_amdgcn_exp2f(vz));
        float y = bni0 + r * (ph * S2 + bh);
        float n = 1.f - 2.f * __builtin_amdgcn_rcpf(1.f + __builtin_amdgcn_exp2f(y));
        h = ok ? (n + z * (h - n)) : 0.f;
    }

    // ---- t = 1 .. 511 : 10 swizzles, 5 independent 5-deep pk chains ----
    #pragma unroll 1
    for (int t = 1; t < STEPS; ++t) {
        v2f h2[5];
        h2[0] = v2f{swz<0>(h), swz<1>(h)};
        h2[1] = v2f{swz<2>(h), swz<3>(h)};
        h2[2] = v2f{swz<4>(h), swz<5>(h)};
        h2[3] = v2f{swz<6>(h), swz<7>(h)};
        h2[4] = v2f{swz<8>(h), swz<9>(h)};

        v2f ar = {br, 0.f}, az = {bz, 0.f}, ai = {bi, 0.f},
            ah = {bh, 0.f}, ao = {bo, 0.f};
        #pragma unroll
        for (int k2 = 0; k2 < 5; ++k2) {
            ar += wr2[k2] * h2[k2];
            az += wz2[k2] * h2[k2];
            ai += wi2[k2] * h2[k2];
            ah += wh2[k2] * h2[k2];
            ao += wo2[k2] * h2[k2];
        }
        float arx = ar.x + ar.y;
        float azx = az.x + az.y;
        float aix = ai.x + ai.y;
        float ahx = ah.x + ah.y;
        float o   = ao.x + ao.y;          // = l1(h_t) = o_{t-1}

        float r = __builtin_amdgcn_rcpf(1.f + __builtin_amdgcn_exp2f(arx));
        float z = __builtin_amdgcn_rcpf(1.f + __builtin_amdgcn_exp2f(azx));
        float zh  = z * h;                // off the n-path: issue early
        float omz = 1.f - z;
        float y = __builtin_fmaf(r, ahx, aix);
        float n = __builtin_fmaf(-2.f,
                    __builtin_amdgcn_rcpf(1.f + __builtin_amdgcn_exp2f(y)), 1.f);
        h = __builtin_fmaf(n, omz, zh);   // == n + z*(h-n); padded lanes stay 0

        if (ok) pb[0] = o;                 // store o_{t-1} (position STEPS-t)
        pb -= HID;
    }

    // ---- epilogue: o_511 = l1(h_512) at position 0 ----
    {
        v2f h2[5];
        h2[0] = v2f{swz<0>(h), swz<1>(h)};
        h2[1] = v2f{swz<2>(h), swz<3>(h)};
        h2[2] = v2f{swz<4>(h), swz<5>(h)};
        h2[3] = v2f{swz<6>(h), swz<7>(h)};
        h2[4] = v2f{swz<8>(h), swz<9>(h)};
        v2f ao = {bo, 0.f};
        #pragma unroll
        for (int k2 = 0; k2 < 5; ++k2) ao += wo2[k2] * h2[k2];
        if (ok) pb[0] = ao.x + ao.y;
    }
}

extern "C" void kernel_launch(void* const* d_in, const int* in_sizes, int n_in,
                              void* d_out, int out_size, void* d_ws, size_t ws_size,
                              hipStream_t stream) {
    (void)in_sizes; (void)n_in; (void)d_ws; (void)ws_size; (void)out_size;
    dim3 grid(2048), block(64);   // 4 batches/wave, 2048 waves -> 2 waves per SIMD
    gru_decoder_kernel<<<grid, block, 0, stream>>>(
        (const float*)d_in[0], (const float*)d_in[1], (const float*)d_in[2],
        (const float*)d_in[3], (const float*)d_in[4], (const float*)d_in[5],
        (const float*)d_in[6], (const float*)d_in[7], (const float*)d_in[8],
        (float*)d_out);
}

// Round 5
// 292.579 us; speedup vs baseline: 1.1948x; 1.0092x over previous
//
#include <hip/hip_runtime.h>

#define HID 10
#define STEPS 512

typedef __attribute__((ext_vector_type(2))) float v2f;
typedef __attribute__((ext_vector_type(4))) float v4f;

// broadcast lane ((lane&0x10)|F) within each 32-lane half -> all lanes of each 16-group
// (one-time use: t=0 peel + epilogue)
template<int F>
static __device__ __forceinline__ float swz(float v) {
    return __int_as_float(__builtin_amdgcn_ds_swizzle(__float_as_int(v), (F << 5) | 0x10));
}

// Lane-parallel fused GRU decoder, 1 feature per lane, 4 batches per wave.
//   batch = blockIdx*4 + (lane>>4); f = lane&15 (f>=10: zero-padded, stores masked)
// v5 = v4 + DS-contention fix:
//   v4 profile: 754 cyc/SIMD-step, VALU issue 437 (58%), 317 cyc BOTH-waves-stalled.
//   Cause: 8 waves/CU x 10 ds_swizzle = 80 DS ops/step, ~464 cyc DS-pipe service
//   (62% bursty utilization -> long queue delay at the gather point).
//   Fix: gather = 1 ds_write_b32 + {b128,b128,b64} broadcast reads (4 DS ops,
//   ~140 cyc/CU-step service). Broadcast reads are conflict-free; write rows
//   stride 16 floats (2-way bank aliasing = free). Single wave per block ->
//   wave-synchronous, in-order DS; compiler order kept via aliasing + fences.
__global__ __launch_bounds__(64, 2) void gru_decoder_kernel(
    const float* __restrict__ hidden, const float* __restrict__ w_ih,
    const float* __restrict__ w_hh, const float* __restrict__ b_ih,
    const float* __restrict__ b_hh, const float* __restrict__ l1_w,
    const float* __restrict__ l1_b, const float* __restrict__ l2_w,
    const float* __restrict__ l2_b, float* __restrict__ out)
{
    __shared__ float sWx[640];   // l2_w @ l1_w (64x10)
    __shared__ float sbx[64];    // l2_w @ l1_b + l2_b
    __shared__ float sWgi[300];  // w_ih @ Wx (30x10)
    __shared__ float sbgi[30];   // b_ih + w_ih @ bx
    __shared__ float sWhh[300];  // w_hh copy (t=0 peel + weight build)
    __shared__ float sH[64];     // 4 groups x 16-float rows (gather staging)

    const int lane = threadIdx.x;
    const int f    = lane & 15;
    const int g    = lane >> 4;
    const int b    = blockIdx.x * 4 + g;
    const bool ok  = (f < HID);
    const int fi   = ok ? f : 0;          // clamped index for safe reads

    // ---- preamble: fused weights (fp32, cooperative) ----
    for (int e = lane; e < 640; e += 64) {
        int i = e / 10, j = e - i * 10;
        float acc = 0.f;
        #pragma unroll
        for (int k = 0; k < 10; ++k) acc += l2_w[i * 10 + k] * l1_w[k * 10 + j];
        sWx[e] = acc;
    }
    {
        float acc = l2_b[lane];
        #pragma unroll
        for (int k = 0; k < 10; ++k) acc += l2_w[lane * 10 + k] * l1_b[k];
        sbx[lane] = acc;
    }
    for (int e = lane; e < 300; e += 64) sWhh[e] = w_hh[e];
    __syncthreads();
    for (int e = lane; e < 300; e += 64) {
        int m = e / 10, j = e - m * 10;
        float acc = 0.f;
        for (int k = 0; k < 64; ++k) acc += w_ih[m * 64 + k] * sWx[k * 10 + j];
        sWgi[e] = acc;
    }
    if (lane < 30) {
        float acc = b_ih[lane];
        for (int k = 0; k < 64; ++k) acc += w_ih[lane * 64 + k] * sbx[k];
        sbgi[lane] = acc;
    }
    __syncthreads();

    const float LOG2E = 1.4426950408889634f;
    const float S2    = 2.f * LOG2E;

    // ---- per-lane weights (feature fi), packed across k (even/odd) ----
    // r,z rows pre-scaled by -LOG2E (sigmoid via exp2 of negated arg);
    // ni,nh rows pre-scaled by 2*LOG2E (tanh via exp2).
    v2f wr2[5], wz2[5], wi2[5], wh2[5], wo2[5];
    #pragma unroll
    for (int k2 = 0; k2 < 5; ++k2) {
        int k0 = 2 * k2, k1 = 2 * k2 + 1;
        float r0 = -(sWgi[fi * 10 + k0] + sWhh[fi * 10 + k0]) * LOG2E;
        float r1 = -(sWgi[fi * 10 + k1] + sWhh[fi * 10 + k1]) * LOG2E;
        float z0 = -(sWgi[(10 + fi) * 10 + k0] + sWhh[(10 + fi) * 10 + k0]) * LOG2E;
        float z1 = -(sWgi[(10 + fi) * 10 + k1] + sWhh[(10 + fi) * 10 + k1]) * LOG2E;
        float i0 = sWgi[(20 + fi) * 10 + k0] * S2;
        float i1 = sWgi[(20 + fi) * 10 + k1] * S2;
        float hh0 = sWhh[(20 + fi) * 10 + k0] * S2;
        float hh1 = sWhh[(20 + fi) * 10 + k1] * S2;
        float o0 = l1_w[fi * 10 + k0];
        float o1 = l1_w[fi * 10 + k1];
        wr2[k2] = ok ? v2f{r0, r1}   : v2f{0.f, 0.f};
        wz2[k2] = ok ? v2f{z0, z1}   : v2f{0.f, 0.f};
        wi2[k2] = ok ? v2f{i0, i1}   : v2f{0.f, 0.f};
        wh2[k2] = ok ? v2f{hh0, hh1} : v2f{0.f, 0.f};
        wo2[k2] = ok ? v2f{o0, o1}   : v2f{0.f, 0.f};
    }
    const float br = ok ? -(sbgi[fi] + b_hh[fi]) * LOG2E : 0.f;
    const float bz = ok ? -(sbgi[10 + fi] + b_hh[10 + fi]) * LOG2E : 0.f;
    const float bi = ok ? sbgi[20 + fi] * S2 : 0.f;
    const float bh = ok ? b_hh[20 + fi] * S2 : 0.f;
    const float bo = ok ? l1_b[fi] : 0.f;
    // t=0 peel biases (gi = b_ih only)
    const float br0_ = ok ? -(b_ih[fi] + b_hh[fi]) * LOG2E : 0.f;
    const float bz0_ = ok ? -(b_ih[10 + fi] + b_hh[10 + fi]) * LOG2E : 0.f;
    const float bni0 = ok ? b_ih[20 + fi] * S2 : 0.f;

    // ---- initial h (one feature per lane; f>=10 stays exactly 0) ----
    float h = ok ? hidden[(size_t)b * HID + f] : 0.f;

    float* pb = out + (size_t)b * (STEPS * HID) + (size_t)(STEPS - 1) * HID + f;
    float* sHrow = &sH[g * 16];

    // ---- t = 0 peeled: gi = b_ih only (x_0 = 0); raw w_hh dots from LDS ----
    // Produces h1. o_0 = l1(h1) is stored by the first loop iteration.
    {
        float ha[10];
        ha[0] = swz<0>(h); ha[1] = swz<1>(h); ha[2] = swz<2>(h);
        ha[3] = swz<3>(h); ha[4] = swz<4>(h); ha[5] = swz<5>(h);
        ha[6] = swz<6>(h); ha[7] = swz<7>(h); ha[8] = swz<8>(h);
        ha[9] = swz<9>(h);
        float pr = 0.f, pz = 0.f, ph = 0.f;
        #pragma unroll
        for (int k = 0; k < 10; ++k) {
            pr += sWhh[fi * 10 + k] * ha[k];
            pz += sWhh[(10 + fi) * 10 + k] * ha[k];
            ph += sWhh[(20 + fi) * 10 + k] * ha[k];
        }
        float vr = br0_ - pr * LOG2E;
        float vz = bz0_ - pz * LOG2E;
        float r = __builtin_amdgcn_rcpf(1.f + __builtin_amdgcn_exp2f(vr));
        float z = __builtin_amdgcn_rcpf(1.f + __builtin_amdgcn_exp2f(vz));
        float y = bni0 + r * (ph * S2 + bh);
        float n = 1.f - 2.f * __builtin_amdgcn_rcpf(1.f + __builtin_amdgcn_exp2f(y));
        h = ok ? (n + z * (h - n)) : 0.f;
    }

    // ---- t = 1 .. 511 : LDS write+broadcast-read gather, 5-deep pk chains ----
    #pragma unroll 1
    for (int t = 1; t < STEPS; ++t) {
        // stage h: all 64 lanes write (rows padded to 16; f>=10 slots unread)
        sHrow[f] = h;
        __builtin_amdgcn_wave_barrier();      // keep write->reads ordered
        __builtin_amdgcn_sched_barrier(0);
        v4f q0 = *(const v4f*)(sHrow);        // h[0..3]  (broadcast read)
        v4f q1 = *(const v4f*)(sHrow + 4);    // h[4..7]
        v2f q2 = *(const v2f*)(sHrow + 8);    // h[8..9]

        v2f h2_0 = __builtin_shufflevector(q0, q0, 0, 1);
        v2f h2_1 = __builtin_shufflevector(q0, q0, 2, 3);
        v2f h2_2 = __builtin_shufflevector(q1, q1, 0, 1);
        v2f h2_3 = __builtin_shufflevector(q1, q1, 2, 3);
        v2f h2_4 = q2;

        v2f ar = {br, 0.f}, az = {bz, 0.f}, ai = {bi, 0.f},
            ah = {bh, 0.f}, ao = {bo, 0.f};
        ar += wr2[0] * h2_0; az += wz2[0] * h2_0; ai += wi2[0] * h2_0;
        ah += wh2[0] * h2_0; ao += wo2[0] * h2_0;
        ar += wr2[1] * h2_1; az += wz2[1] * h2_1; ai += wi2[1] * h2_1;
        ah += wh2[1] * h2_1; ao += wo2[1] * h2_1;
        ar += wr2[2] * h2_2; az += wz2[2] * h2_2; ai += wi2[2] * h2_2;
        ah += wh2[2] * h2_2; ao += wo2[2] * h2_2;
        ar += wr2[3] * h2_3; az += wz2[3] * h2_3; ai += wi2[3] * h2_3;
        ah += wh2[3] * h2_3; ao += wo2[3] * h2_3;
        ar += wr2[4] * h2_4; az += wz2[4] * h2_4; ai += wi2[4] * h2_4;
        ah += wh2[4] * h2_4; ao += wo2[4] * h2_4;

        float arx = ar.x + ar.y;
        float azx = az.x + az.y;
        float aix = ai.x + ai.y;
        float ahx = ah.x + ah.y;
        float o   = ao.x + ao.y;          // = l1(h_t) = o_{t-1}

        float r = __builtin_amdgcn_rcpf(1.f + __builtin_amdgcn_exp2f(arx));
        float z = __builtin_amdgcn_rcpf(1.f + __builtin_amdgcn_exp2f(azx));
        float zh  = z * h;                // off the n-path: issue early
        float omz = 1.f - z;
        float y = __builtin_fmaf(r, ahx, aix);
        float n = __builtin_fmaf(-2.f,
                    __builtin_amdgcn_rcpf(1.f + __builtin_amdgcn_exp2f(y)), 1.f);
        h = __builtin_fmaf(n, omz, zh);   // == n + z*(h-n); padded lanes stay 0

        if (ok) pb[0] = o;                 // store o_{t-1} (position STEPS-t)
        pb -= HID;
    }

    // ---- epilogue: o_511 = l1(h_512) at position 0 ----
    {
        v2f h2[5];
        h2[0] = v2f{swz<0>(h), swz<1>(h)};
        h2[1] = v2f{swz<2>(h), swz<3>(h)};
        h2[2] = v2f{swz<4>(h), swz<5>(h)};
        h2[3] = v2f{swz<6>(h), swz<7>(h)};
        h2[4] = v2f{swz<8>(h), swz<9>(h)};
        v2f ao = {bo, 0.f};
        #pragma unroll
        for (int k2 = 0; k2 < 5; ++k2) ao += wo2[k2] * h2[k2];
        if (ok) pb[0] = ao.x + ao.y;
    }
}

extern "C" void kernel_launch(void* const* d_in, const int* in_sizes, int n_in,
                              void* d_out, int out_size, void* d_ws, size_t ws_size,
                              hipStream_t stream) {
    (void)in_sizes; (void)n_in; (void)d_ws; (void)ws_size; (void)out_size;
    dim3 grid(2048), block(64);   // 4 batches/wave, 2048 waves -> 2 waves per SIMD
    gru_decoder_kernel<<<grid, block, 0, stream>>>(
        (const float*)d_in[0], (const float*)d_in[1], (const float*)d_in[2],
        (const float*)d_in[3], (const float*)d_in[4], (const float*)d_in[5],
        (const float*)d_in[6], (const float*)d_in[7], (const float*)d_in[8],
        (float*)d_out);
}

// Round 7
// 291.309 us; speedup vs baseline: 1.2000x; 1.0044x over previous
//
#include <hip/hip_runtime.h>

#define HID 10
#define STEPS 512

typedef __attribute__((ext_vector_type(2))) float v2f;
typedef __attribute__((ext_vector_type(4))) float v4f;

// broadcast lane ((lane&0x10)|F) within each 32-lane half -> all lanes of each 16-group
// (one-time use: t=0 peel + epilogue)
template<int F>
static __device__ __forceinline__ float swz(float v) {
    return __int_as_float(__builtin_amdgcn_ds_swizzle(__float_as_int(v), (F << 5) | 0x10));
}

// Lane-parallel fused GRU decoder, 1 feature per lane, 4 batches per wave.
//   batch = blockIdx*4 + (lane>>4); f = lane&15 (f>=10: zero-padded, stores masked)
// v6 = v5 + three stall/issue cuts (v5 profile: 735 cyc/SIMD-step = 434 issue +
// ~300 dual-wave stall; the 2 resident waves run in lockstep convoy, ~zero overlap):
//  (a) anti-phase stagger: one-time s_sleep of 0..3 x ~192cy keyed on
//      (blockIdx>>3)&3 (blocks 8 apart share an XCD). De-phased partner waves
//      fill each other's chain-stalls; offsets persist (fixed-latency stalls).
//  (b) z/n fused update, one rcp instead of two:
//      h' = (ez(en-1) + h(en+1)) / ((en+1)(1+ez)), ez=exp2(azx), en=exp2(y).
//  (c) accumulator init via fma into resident v2f bias consts (kills 10 movs).
// (Round-6 submission never ran: container-level infra failure. Resubmitted.)
__global__ __launch_bounds__(64, 2) void gru_decoder_kernel(
    const float* __restrict__ hidden, const float* __restrict__ w_ih,
    const float* __restrict__ w_hh, const float* __restrict__ b_ih,
    const float* __restrict__ b_hh, const float* __restrict__ l1_w,
    const float* __restrict__ l1_b, const float* __restrict__ l2_w,
    const float* __restrict__ l2_b, float* __restrict__ out)
{
    __shared__ float sWx[640];   // l2_w @ l1_w (64x10)
    __shared__ float sbx[64];    // l2_w @ l1_b + l2_b
    __shared__ float sWgi[300];  // w_ih @ Wx (30x10)
    __shared__ float sbgi[30];   // b_ih + w_ih @ bx
    __shared__ float sWhh[300];  // w_hh copy (t=0 peel + weight build)
    __shared__ float sH[64];     // 4 groups x 16-float rows (gather staging)

    const int lane = threadIdx.x;
    const int f    = lane & 15;
    const int g    = lane >> 4;
    const int b    = blockIdx.x * 4 + g;
    const bool ok  = (f < HID);
    const int fi   = ok ? f : 0;          // clamped index for safe reads

    // ---- preamble: fused weights (fp32, cooperative) ----
    for (int e = lane; e < 640; e += 64) {
        int i = e / 10, j = e - i * 10;
        float acc = 0.f;
        #pragma unroll
        for (int k = 0; k < 10; ++k) acc += l2_w[i * 10 + k] * l1_w[k * 10 + j];
        sWx[e] = acc;
    }
    {
        float acc = l2_b[lane];
        #pragma unroll
        for (int k = 0; k < 10; ++k) acc += l2_w[lane * 10 + k] * l1_b[k];
        sbx[lane] = acc;
    }
    for (int e = lane; e < 300; e += 64) sWhh[e] = w_hh[e];
    __syncthreads();
    for (int e = lane; e < 300; e += 64) {
        int m = e / 10, j = e - m * 10;
        float acc = 0.f;
        for (int k = 0; k < 64; ++k) acc += w_ih[m * 64 + k] * sWx[k * 10 + j];
        sWgi[e] = acc;
    }
    if (lane < 30) {
        float acc = b_ih[lane];
        for (int k = 0; k < 64; ++k) acc += w_ih[lane * 64 + k] * sbx[k];
        sbgi[lane] = acc;
    }
    __syncthreads();

    const float LOG2E = 1.4426950408889634f;
    const float S2    = 2.f * LOG2E;

    // ---- per-lane weights (feature fi), packed across k (even/odd) ----
    // r,z rows pre-scaled by -LOG2E (sigmoid via exp2 of negated arg);
    // ni,nh rows pre-scaled by 2*LOG2E (tanh via exp2).
    v2f wr2[5], wz2[5], wi2[5], wh2[5], wo2[5];
    #pragma unroll
    for (int k2 = 0; k2 < 5; ++k2) {
        int k0 = 2 * k2, k1 = 2 * k2 + 1;
        float r0 = -(sWgi[fi * 10 + k0] + sWhh[fi * 10 + k0]) * LOG2E;
        float r1 = -(sWgi[fi * 10 + k1] + sWhh[fi * 10 + k1]) * LOG2E;
        float z0 = -(sWgi[(10 + fi) * 10 + k0] + sWhh[(10 + fi) * 10 + k0]) * LOG2E;
        float z1 = -(sWgi[(10 + fi) * 10 + k1] + sWhh[(10 + fi) * 10 + k1]) * LOG2E;
        float i0 = sWgi[(20 + fi) * 10 + k0] * S2;
        float i1 = sWgi[(20 + fi) * 10 + k1] * S2;
        float hh0 = sWhh[(20 + fi) * 10 + k0] * S2;
        float hh1 = sWhh[(20 + fi) * 10 + k1] * S2;
        float o0 = l1_w[fi * 10 + k0];
        float o1 = l1_w[fi * 10 + k1];
        wr2[k2] = ok ? v2f{r0, r1}   : v2f{0.f, 0.f};
        wz2[k2] = ok ? v2f{z0, z1}   : v2f{0.f, 0.f};
        wi2[k2] = ok ? v2f{i0, i1}   : v2f{0.f, 0.f};
        wh2[k2] = ok ? v2f{hh0, hh1} : v2f{0.f, 0.f};
        wo2[k2] = ok ? v2f{o0, o1}   : v2f{0.f, 0.f};
    }
    const float br = ok ? -(sbgi[fi] + b_hh[fi]) * LOG2E : 0.f;
    const float bz = ok ? -(sbgi[10 + fi] + b_hh[10 + fi]) * LOG2E : 0.f;
    const float bi = ok ? sbgi[20 + fi] * S2 : 0.f;
    const float bh = ok ? b_hh[20 + fi] * S2 : 0.f;
    const float bo = ok ? l1_b[fi] : 0.f;
    // resident v2f bias consts (fma-init of the dot chains; kills 10 movs/iter)
    const v2f BR2 = {br, 0.f}, BZ2 = {bz, 0.f}, BI2 = {bi, 0.f},
              BH2 = {bh, 0.f}, BO2 = {bo, 0.f};
    // t=0 peel biases (gi = b_ih only)
    const float br0_ = ok ? -(b_ih[fi] + b_hh[fi]) * LOG2E : 0.f;
    const float bz0_ = ok ? -(b_ih[10 + fi] + b_hh[10 + fi]) * LOG2E : 0.f;
    const float bni0 = ok ? b_ih[20 + fi] * S2 : 0.f;

    // ---- initial h (one feature per lane; f>=10 stays exactly 0) ----
    float h = ok ? hidden[(size_t)b * HID + f] : 0.f;

    float* pb = out + (size_t)b * (STEPS * HID) + (size_t)(STEPS - 1) * HID + f;
    float* sHrow = &sH[g * 16];

    // ---- t = 0 peeled: gi = b_ih only (x_0 = 0); raw w_hh dots from LDS ----
    // Produces h1. o_0 = l1(h1) is stored by the first loop iteration.
    {
        float ha[10];
        ha[0] = swz<0>(h); ha[1] = swz<1>(h); ha[2] = swz<2>(h);
        ha[3] = swz<3>(h); ha[4] = swz<4>(h); ha[5] = swz<5>(h);
        ha[6] = swz<6>(h); ha[7] = swz<7>(h); ha[8] = swz<8>(h);
        ha[9] = swz<9>(h);
        float pr = 0.f, pz = 0.f, ph = 0.f;
        #pragma unroll
        for (int k = 0; k < 10; ++k) {
            pr += sWhh[fi * 10 + k] * ha[k];
            pz += sWhh[(10 + fi) * 10 + k] * ha[k];
            ph += sWhh[(20 + fi) * 10 + k] * ha[k];
        }
        float vr = br0_ - pr * LOG2E;
        float vz = bz0_ - pz * LOG2E;
        float r = __builtin_amdgcn_rcpf(1.f + __builtin_amdgcn_exp2f(vr));
        float z = __builtin_amdgcn_rcpf(1.f + __builtin_amdgcn_exp2f(vz));
        float y = bni0 + r * (ph * S2 + bh);
        float n = 1.f - 2.f * __builtin_amdgcn_rcpf(1.f + __builtin_amdgcn_exp2f(y));
        h = ok ? (n + z * (h - n)) : 0.f;
    }

    // ---- anti-phase stagger: de-convoy the co-resident waves (one-time) ----
    {
        int ph = (blockIdx.x >> 3) & 3;
        if (ph & 1) __builtin_amdgcn_s_sleep(3);                              // ~192cy
        if (ph & 2) { __builtin_amdgcn_s_sleep(3); __builtin_amdgcn_s_sleep(3); } // ~384cy
    }

    // ---- t = 1 .. 511 : LDS write+broadcast-read gather, 5-deep pk chains ----
    #pragma unroll 1
    for (int t = 1; t < STEPS; ++t) {
        // stage h: all 64 lanes write (rows padded to 16; f>=10 slots unread)
        sHrow[f] = h;
        __builtin_amdgcn_wave_barrier();      // keep write->reads ordered
        __builtin_amdgcn_sched_barrier(0);
        v4f q0 = *(const v4f*)(sHrow);        // h[0..3]  (broadcast read)
        v4f q1 = *(const v4f*)(sHrow + 4);    // h[4..7]
        v2f q2 = *(const v2f*)(sHrow + 8);    // h[8..9]

        v2f h2_0 = __builtin_shufflevector(q0, q0, 0, 1);
        v2f h2_1 = __builtin_shufflevector(q0, q0, 2, 3);
        v2f h2_2 = __builtin_shufflevector(q1, q1, 0, 1);
        v2f h2_3 = __builtin_shufflevector(q1, q1, 2, 3);
        v2f h2_4 = q2;

        // fma-init into bias consts (no accumulator movs)
        v2f ar = wr2[0] * h2_0 + BR2;
        v2f az = wz2[0] * h2_0 + BZ2;
        v2f ai = wi2[0] * h2_0 + BI2;
        v2f ah = wh2[0] * h2_0 + BH2;
        v2f ao = wo2[0] * h2_0 + BO2;
        ar += wr2[1] * h2_1; az += wz2[1] * h2_1; ai += wi2[1] * h2_1;
        ah += wh2[1] * h2_1; ao += wo2[1] * h2_1;
        ar += wr2[2] * h2_2; az += wz2[2] * h2_2; ai += wi2[2] * h2_2;
        ah += wh2[2] * h2_2; ao += wo2[2] * h2_2;
        ar += wr2[3] * h2_3; az += wz2[3] * h2_3; ai += wi2[3] * h2_3;
        ah += wh2[3] * h2_3; ao += wo2[3] * h2_3;
        ar += wr2[4] * h2_4; az += wz2[4] * h2_4; ai += wi2[4] * h2_4;
        ah += wh2[4] * h2_4; ao += wo2[4] * h2_4;

        float arx = ar.x + ar.y;
        float azx = az.x + az.y;
        float aix = ai.x + ai.y;
        float ahx = ah.x + ah.y;
        float o   = ao.x + ao.y;          // = l1(h_t) = o_{t-1}

        // r-gate (unchanged), then fused z/n update with a single rcp:
        //   h' = (ez*(en-1) + h*(en+1)) / ((en+1)*(1+ez))
        float er = __builtin_amdgcn_exp2f(arx);
        float r  = __builtin_amdgcn_rcpf(1.f + er);
        float ez = __builtin_amdgcn_exp2f(azx);
        float y  = __builtin_fmaf(r, ahx, aix);
        float en = __builtin_amdgcn_exp2f(y);
        float p  = en * ez;
        float tt = h - ez;
        float u  = p + tt;
        float num = __builtin_fmaf(h, en, u);          // ez*en - ez + h*en + h
        float v   = en + ez;
        float den = (p + v) + 1.f;                     // (en+1)*(1+ez)
        h = num * __builtin_amdgcn_rcpf(den);          // padded lanes: h stays 0

        if (ok) pb[0] = o;                 // store o_{t-1} (position STEPS-t)
        pb -= HID;
    }

    // ---- epilogue: o_511 = l1(h_512) at position 0 ----
    {
        v2f h2[5];
        h2[0] = v2f{swz<0>(h), swz<1>(h)};
        h2[1] = v2f{swz<2>(h), swz<3>(h)};
        h2[2] = v2f{swz<4>(h), swz<5>(h)};
        h2[3] = v2f{swz<6>(h), swz<7>(h)};
        h2[4] = v2f{swz<8>(h), swz<9>(h)};
        v2f ao = {bo, 0.f};
        #pragma unroll
        for (int k2 = 0; k2 < 5; ++k2) ao += wo2[k2] * h2[k2];
        if (ok) pb[0] = ao.x + ao.y;
    }
}

extern "C" void kernel_launch(void* const* d_in, const int* in_sizes, int n_in,
                              void* d_out, int out_size, void* d_ws, size_t ws_size,
                              hipStream_t stream) {
    (void)in_sizes; (void)n_in; (void)d_ws; (void)ws_size; (void)out_size;
    dim3 grid(2048), block(64);   // 4 batches/wave, 2048 waves -> 2 waves per SIMD
    gru_decoder_kernel<<<grid, block, 0, stream>>>(
        (const float*)d_in[0], (const float*)d_in[1], (const float*)d_in[2],
        (const float*)d_in[3], (const float*)d_in[4], (const float*)d_in[5],
        (const float*)d_in[6], (const float*)d_in[7], (const float*)d_in[8],
        (float*)d_out);
}